// Round 11
// baseline (242.971 us; speedup 1.0000x reference)
//
#include <hip/hip_runtime.h>

typedef unsigned short u16;
typedef unsigned int u32;
typedef __attribute__((ext_vector_type(8))) short s16x8;
typedef __attribute__((ext_vector_type(4))) float f32x4;

#define NN 50000
#define NE 600000
#define NG 64

__device__ __forceinline__ u16 f2bf(float f) {
    u32 u = __float_as_uint(f);
    u32 r = (u + 0x7fffu + ((u >> 16) & 1u)) >> 16;
    return (u16)r;
}
__device__ __forceinline__ float bf2f(u16 h) {
    return __uint_as_float(((u32)h) << 16);
}

// ---------------- CSR build ----------------
__global__ void k_hist(const int* __restrict__ dst, int* __restrict__ cnt, int ne) {
    int e = blockIdx.x * blockDim.x + threadIdx.x;
    if (e < ne) atomicAdd(&cnt[dst[e]], 1);
}

__global__ __launch_bounds__(256)
void k_scan1(const int* __restrict__ cnt, int* __restrict__ bsum, int n) {
    int i = blockIdx.x * 256 + threadIdx.x;
    int v = (i < n) ? cnt[i] : 0;
#pragma unroll
    for (int off = 32; off > 0; off >>= 1) v += __shfl_down(v, off, 64);
    __shared__ int ws[4];
    int lane = threadIdx.x & 63, w = threadIdx.x >> 6;
    if (lane == 0) ws[w] = v;
    __syncthreads();
    if (threadIdx.x == 0) bsum[blockIdx.x] = ws[0] + ws[1] + ws[2] + ws[3];
}

__global__ __launch_bounds__(256)
void k_scan2(int* __restrict__ bsum, int nb) {
    int t = threadIdx.x;
    int v = (t < nb) ? bsum[t] : 0;
    int lane = t & 63, w = t >> 6;
    int inc = v;
#pragma unroll
    for (int off = 1; off < 64; off <<= 1) {
        int x = __shfl_up(inc, off, 64);
        if (lane >= off) inc += x;
    }
    __shared__ int wtot[4];
    if (lane == 63) wtot[w] = inc;
    __syncthreads();
    int wo = 0;
    for (int j = 0; j < w; ++j) wo += wtot[j];
    if (t < nb) bsum[t] = wo + inc - v;   // exclusive
}

__global__ __launch_bounds__(256)
void k_scan3(const int* __restrict__ cnt, const int* __restrict__ boff,
             int* __restrict__ rowptr, int* __restrict__ cursor,
             float* __restrict__ dinv, int n) {
    int i = blockIdx.x * 256 + threadIdx.x;
    int v = (i < n) ? cnt[i] : 0;
    int lane = threadIdx.x & 63, w = threadIdx.x >> 6;
    int inc = v;
#pragma unroll
    for (int off = 1; off < 64; off <<= 1) {
        int x = __shfl_up(inc, off, 64);
        if (lane >= off) inc += x;
    }
    __shared__ int wtot[4];
    if (lane == 63) wtot[w] = inc;
    __syncthreads();
    int wo = boff[blockIdx.x];
    for (int j = 0; j < w; ++j) wo += wtot[j];
    if (i < n) {
        int excl = wo + inc - v;
        rowptr[i] = excl;
        cursor[i] = excl;
        dinv[i] = rsqrtf(1.0f + (float)v);
        if (i == n - 1) rowptr[n] = excl + v;
    }
}

__global__ void k_fill(const int* __restrict__ src, const int* __restrict__ dst,
                       int* __restrict__ cursor, int* __restrict__ csr_src, int ne) {
    int e = blockIdx.x * blockDim.x + threadIdx.x;
    if (e < ne) {
        int pos = atomicAdd(&cursor[dst[e]], 1);
        csr_src[pos] = src[e];
    }
}

// ---------------- fused preamble ----------------
// Weight split is stored PRE-TILED: wt[kgrp][n][8] with k = kgrp*8 + j
__device__ __forceinline__ void wsplit_tiled(const float* __restrict__ W,
                                             u16* __restrict__ hi, u16* __restrict__ lo,
                                             int gid) {
    int n = gid & 255, kgrp = gid >> 8;
    int kbase = kgrp * 8;
#pragma unroll
    for (int j = 0; j < 8; ++j) {
        float w = W[(size_t)(kbase + j) * 256 + n];
        u16 h = f2bf(w);
        hi[(size_t)gid * 8 + j] = h;
        lo[(size_t)gid * 8 + j] = f2bf(w - bf2f(h));
    }
}

// block ranges: [0,XB) xbf | [16) W1 | [32) W2 | [64) sums | [CB) cnt | [1] counts
__global__ __launch_bounds__(256)
void k_preamble(const float* __restrict__ x, u16* __restrict__ xbf,
                const float* __restrict__ W1, u16* __restrict__ w1hi, u16* __restrict__ w1lo,
                const float* __restrict__ W2, u16* __restrict__ w2hi, u16* __restrict__ w2lo,
                float* __restrict__ sums, int* __restrict__ cnt,
                const int* __restrict__ batch, float* __restrict__ counts) {
    const int XB = (NN * 32 + 255) / 256;        // x as float4: N*128/4 elems
    const int CB = (NN + 255) / 256;
    int b = blockIdx.x, t = threadIdx.x;
    if (b < XB) {
        int i = b * 256 + t;
        if (i < NN * 32) {
            float4 v = ((const float4*)x)[i];
            ushort4 o;
            o.x = f2bf(v.x); o.y = f2bf(v.y); o.z = f2bf(v.z); o.w = f2bf(v.w);
            ((ushort4*)xbf)[i] = o;
        }
        return;
    }
    b -= XB;
    if (b < 16) { wsplit_tiled(W1, w1hi, w1lo, b * 256 + t); return; }   // 4096 groups
    b -= 16;
    if (b < 32) { wsplit_tiled(W2, w2hi, w2lo, b * 256 + t); return; }   // 8192 groups
    b -= 32;
    if (b < 64) { sums[b * 256 + t] = 0.f; return; }
    b -= 64;
    if (b < CB) {
        int i = b * 256 + t;
        if (i < NN) cnt[i] = 0;
        return;
    }
    b -= CB;
    if (b == 0) {   // counts via binary search on sorted batch
        __shared__ int lb[65];
        if (t <= 64) {
            int lo = 0, hi = NN;
            while (lo < hi) {
                int mid = (lo + hi) >> 1;
                if (batch[mid] < t) lo = mid + 1; else hi = mid;
            }
            lb[t] = lo;
        }
        __syncthreads();
        if (t < 64) counts[t] = (float)(lb[t + 1] - lb[t]);
    }
}

// ---------------- gather aggregation: 2 nodes/wave, 32 lanes/node ----------------
__device__ __forceinline__ void fma8(float* a, const uint4& v, float w) {
    a[0] += bf2f((u16)v.x) * w; a[1] += bf2f((u16)(v.x >> 16)) * w;
    a[2] += bf2f((u16)v.y) * w; a[3] += bf2f((u16)(v.y >> 16)) * w;
    a[4] += bf2f((u16)v.z) * w; a[5] += bf2f((u16)(v.z >> 16)) * w;
    a[6] += bf2f((u16)v.w) * w; a[7] += bf2f((u16)(v.w >> 16)) * w;
}
__device__ __forceinline__ void fma4(float* a, const uint2& v, float w) {
    a[0] += bf2f((u16)v.x) * w; a[1] += bf2f((u16)(v.x >> 16)) * w;
    a[2] += bf2f((u16)v.y) * w; a[3] += bf2f((u16)(v.y >> 16)) * w;
}

template<int C>   // C=256: uint4/lane (8 bf16); C=128: uint2/lane (4 bf16)
__global__ __launch_bounds__(256)
void k_agg_gather(const int* __restrict__ rowptr, const int* __restrict__ csr_src,
                  const float* __restrict__ dinv, const u16* __restrict__ hb,
                  u16* __restrict__ out, int n) {
    constexpr int VL = C / 32;           // bf16 per lane (8 or 4)
    int tid = threadIdx.x;
    int node = (blockIdx.x * 256 + tid) >> 5;
    if (node >= n) return;
    int sl = tid & 31;                   // lane within node's 32-lane group
    int hbase = tid & 32;                // this half's lane base within the wave
    int beg = rowptr[node], end = rowptr[node + 1];
    int m = end - beg;
    float di = dinv[node];
    float a0[VL], a1[VL];
    if constexpr (VL == 8) {
        uint4 v = ((const uint4*)hb)[(size_t)node * 32 + sl];
#pragma unroll
        for (int i = 0; i < 8; ++i) a1[i] = 0.f;
        a0[0] = bf2f((u16)v.x) * di; a0[1] = bf2f((u16)(v.x >> 16)) * di;
        a0[2] = bf2f((u16)v.y) * di; a0[3] = bf2f((u16)(v.y >> 16)) * di;
        a0[4] = bf2f((u16)v.z) * di; a0[5] = bf2f((u16)(v.z >> 16)) * di;
        a0[6] = bf2f((u16)v.w) * di; a0[7] = bf2f((u16)(v.w >> 16)) * di;
    } else {
        uint2 v = ((const uint2*)hb)[(size_t)node * 32 + sl];
#pragma unroll
        for (int i = 0; i < 4; ++i) a1[i] = 0.f;
        a0[0] = bf2f((u16)v.x) * di; a0[1] = bf2f((u16)(v.x >> 16)) * di;
        a0[2] = bf2f((u16)v.y) * di; a0[3] = bf2f((u16)(v.y >> 16)) * di;
    }
    for (int base = 0; base < m; base += 32) {
        int c = m - base; if (c > 32) c = 32;
        int sid = 0; float w = 0.f;      // padding lanes: node 0 with weight 0 (harmless)
        if (sl < c) { sid = csr_src[beg + base + sl]; w = dinv[sid]; }
        int cr = (c + 3) & ~3;           // round up: no serial tail
        for (int e = 0; e < cr; e += 4) {
            int   s0 = __shfl(sid, hbase + e, 64),     s1 = __shfl(sid, hbase + e + 1, 64);
            int   s2 = __shfl(sid, hbase + e + 2, 64), s3 = __shfl(sid, hbase + e + 3, 64);
            float w0 = __shfl(w, hbase + e, 64),       w1 = __shfl(w, hbase + e + 1, 64);
            float w2 = __shfl(w, hbase + e + 2, 64),   w3 = __shfl(w, hbase + e + 3, 64);
            if constexpr (VL == 8) {
                uint4 r0 = ((const uint4*)hb)[(size_t)s0 * 32 + sl];
                uint4 r1 = ((const uint4*)hb)[(size_t)s1 * 32 + sl];
                uint4 r2 = ((const uint4*)hb)[(size_t)s2 * 32 + sl];
                uint4 r3 = ((const uint4*)hb)[(size_t)s3 * 32 + sl];
                fma8(a0, r0, w0); fma8(a1, r1, w1); fma8(a0, r2, w2); fma8(a1, r3, w3);
            } else {
                uint2 r0 = ((const uint2*)hb)[(size_t)s0 * 32 + sl];
                uint2 r1 = ((const uint2*)hb)[(size_t)s1 * 32 + sl];
                uint2 r2 = ((const uint2*)hb)[(size_t)s2 * 32 + sl];
                uint2 r3 = ((const uint2*)hb)[(size_t)s3 * 32 + sl];
                fma4(a0, r0, w0); fma4(a1, r1, w1); fma4(a0, r2, w2); fma4(a1, r3, w3);
            }
        }
    }
    if constexpr (VL == 8) {
        uint4 o;
        o.x = (u32)f2bf((a0[0] + a1[0]) * di) | ((u32)f2bf((a0[1] + a1[1]) * di) << 16);
        o.y = (u32)f2bf((a0[2] + a1[2]) * di) | ((u32)f2bf((a0[3] + a1[3]) * di) << 16);
        o.z = (u32)f2bf((a0[4] + a1[4]) * di) | ((u32)f2bf((a0[5] + a1[5]) * di) << 16);
        o.w = (u32)f2bf((a0[6] + a1[6]) * di) | ((u32)f2bf((a0[7] + a1[7]) * di) << 16);
        ((uint4*)out)[(size_t)node * 32 + sl] = o;
    } else {
        uint2 o;
        o.x = (u32)f2bf((a0[0] + a1[0]) * di) | ((u32)f2bf((a0[1] + a1[1]) * di) << 16);
        o.y = (u32)f2bf((a0[2] + a1[2]) * di) | ((u32)f2bf((a0[3] + a1[3]) * di) << 16);
        ((uint2*)out)[(size_t)node * 32 + sl] = o;
    }
}

// ---------------- register MFMA GEMM: BM=64, BN=256, 256 thr / 4 waves ----------------
// NO LDS, NO barriers. Each wave owns all 64 rows x its 64-col strip, accumulators in
// registers. A fragments read directly (L2/L3, 4x wave redundancy); B fragments from
// the pre-tiled [kgrp][n][8] split arrays (L2-resident). Full K unroll (template KK):
// compiler software-pipelines freely; latency hidden by ~16 waves/CU TLP.
template<bool POOL, int KK>
__global__ __launch_bounds__(256)
void k_gemm_reg(const u16* __restrict__ A, const u16* __restrict__ Bhi,
                const u16* __restrict__ Blo,
                const float* __restrict__ bias, u16* __restrict__ out_bf,
                const int* __restrict__ batch, float* __restrict__ pool,
                int M) {
    const int lane = threadIdx.x & 63, wid = threadIdx.x >> 6;
    const int bm = blockIdx.x * 64;
    const int wc = wid * 64;
    const int lr = lane & 15, kg = lane >> 4;

    // per-fm A row addresses (clamped)
    const u16* arow[4];
#pragma unroll
    for (int fm = 0; fm < 4; ++fm) {
        int row = bm + fm * 16 + lr;
        if (row >= M) row = M - 1;
        arow[fm] = A + (size_t)row * KK + kg * 8;
    }
    // B fragment base: pre-tiled idx = ((t*4+kg)*256 + wc+fn*16+lr)*8
    const u16* bh_p = Bhi + ((u32)kg * 256 + wc + lr) * 8;
    const u16* bl_p = Blo + ((u32)kg * 256 + wc + lr) * 8;

    f32x4 acc[4][4];
#pragma unroll
    for (int i = 0; i < 4; ++i)
#pragma unroll
        for (int j = 0; j < 4; ++j) acc[i][j] = (f32x4){0.f, 0.f, 0.f, 0.f};

#pragma unroll
    for (int t = 0; t < KK / 32; ++t) {
        s16x8 a[4], bh[4], bl[4];
#pragma unroll
        for (int fm = 0; fm < 4; ++fm)
            a[fm] = *(const s16x8*)(arow[fm] + t * 32);
#pragma unroll
        for (int fn = 0; fn < 4; ++fn) {
            u32 off = (u32)t * 8192 + (u32)fn * 128;
            bh[fn] = *(const s16x8*)&bh_p[off];
            bl[fn] = *(const s16x8*)&bl_p[off];
        }
#pragma unroll
        for (int fn = 0; fn < 4; ++fn)
#pragma unroll
            for (int fm = 0; fm < 4; ++fm) {
                acc[fm][fn] = __builtin_amdgcn_mfma_f32_16x16x32_bf16(a[fm], bh[fn], acc[fm][fn], 0, 0, 0);
                acc[fm][fn] = __builtin_amdgcn_mfma_f32_16x16x32_bf16(a[fm], bl[fn], acc[fm][fn], 0, 0, 0);
            }
    }

    // epilogue: row = bm + fm*16 + kg*4 + r ; col = wc + fn*16 + lr
#pragma unroll
    for (int fn = 0; fn < 4; ++fn) {
        int col = wc + fn * 16 + lr;
        float bv = bias[col];
        if (!POOL) {
#pragma unroll
            for (int fm = 0; fm < 4; ++fm) {
                int rbase = bm + fm * 16 + kg * 4;
#pragma unroll
                for (int r = 0; r < 4; ++r) {
                    int row = rbase + r;
                    if (row < M)
                        out_bf[(size_t)row * 256 + col] = f2bf(fmaxf(acc[fm][fn][r] + bv, 0.f));
                }
            }
        } else {
            int gcur = -1;
            float run = 0.f;
#pragma unroll
            for (int fm = 0; fm < 4; ++fm) {
                int rbase = bm + fm * 16 + kg * 4;
#pragma unroll
                for (int r = 0; r < 4; ++r) {
                    int row = rbase + r;
                    if (row < M) {
                        int g = batch[row];
                        float v = fmaxf(acc[fm][fn][r] + bv, 0.f);
                        if (g != gcur) {
                            if (gcur >= 0) atomicAdd(&pool[gcur * 256 + col], run);
                            gcur = g;
                            run = 0.f;
                        }
                        run += v;
                    }
                }
            }
            if (gcur >= 0) atomicAdd(&pool[gcur * 256 + col], run);
        }
    }
}

// ---------------- dense head ----------------
__global__ __launch_bounds__(128)
void k_dense(const float* __restrict__ sums, const float* __restrict__ counts,
             const float* __restrict__ W3, const float* __restrict__ b3,
             const float* __restrict__ W4, const float* __restrict__ b4,
             float* __restrict__ out) {
    __shared__ float g[256];
    __shared__ float hid[128];
    int gi = blockIdx.x;
    int t = threadIdx.x;
    float inv = 1.0f / fmaxf(counts[gi], 1.0f);
    for (int c = t; c < 256; c += 128) g[c] = sums[gi * 256 + c] * inv;
    __syncthreads();
    float acc = b3[t];
    for (int k = 0; k < 256; ++k) acc += g[k] * W3[k * 128 + t];
    hid[t] = fmaxf(acc, 0.0f);
    __syncthreads();
    if (t < 10) {
        float o = b4[t];
        for (int k = 0; k < 128; ++k) o += hid[k] * W4[k * 10 + t];
        out[gi * 10 + t] = o;
    }
}

extern "C" void kernel_launch(void* const* d_in, const int* in_sizes, int n_in,
                              void* d_out, int out_size, void* d_ws, size_t ws_size,
                              hipStream_t stream) {
    const float* x   = (const float*)d_in[0];
    const int*  eidx = (const int*)d_in[1];    // [2, NE]
    const int*  batch= (const int*)d_in[2];
    const float* W1 = (const float*)d_in[3];
    const float* b1 = (const float*)d_in[4];
    const float* W2 = (const float*)d_in[5];
    const float* b2 = (const float*)d_in[6];
    const float* W3 = (const float*)d_in[7];
    const float* b3 = (const float*)d_in[8];
    const float* W4 = (const float*)d_in[9];
    const float* b4 = (const float*)d_in[10];
    float* out = (float*)d_out;

    const int N = NN, E = NE, G = NG;
    const int* src = eidx;
    const int* dst = eidx + E;
    const int NB = (N + 255) / 256;

    // workspace layout (256B-aligned slices)
    char* p = (char*)d_ws;
    auto alloc = [&](size_t bytes) { char* r = p; p += (bytes + 255) & ~(size_t)255; return r; };
    u16*   h1bf   = (u16*)alloc((size_t)N * 256 * 2);   // bf16 h1 (gather source for conv2)
    u16*   xbf    = (u16*)alloc((size_t)N * 128 * 2);   // bf16 x  (gather source for conv1)
    float* dinv   = (float*)alloc((size_t)N * 4);
    float* sums   = (float*)alloc((size_t)G * 256 * 4);
    float* counts = (float*)alloc((size_t)G * 4);
    int*   cnt    = (int*)alloc((size_t)N * 4);         // reused as cursor after scan
    int*   rowptr = (int*)alloc((size_t)(N + 1) * 4);
    int*   bsum   = (int*)alloc((size_t)NB * 4);
    int*   csr    = (int*)alloc((size_t)E * 4);
    u16*   agg1   = (u16*)alloc((size_t)N * 128 * 2);   // bf16 aggregated x (GEMM1 A)
    u16*   agg2   = (u16*)alloc((size_t)N * 256 * 2);   // bf16 aggregated h1 (GEMM2 A)
    u16*   w1hi   = (u16*)alloc((size_t)256 * 128 * 2); // pre-tiled [kgrp][n][8]
    u16*   w1lo   = (u16*)alloc((size_t)256 * 128 * 2);
    u16*   w2hi   = (u16*)alloc((size_t)256 * 256 * 2);
    u16*   w2lo   = (u16*)alloc((size_t)256 * 256 * 2);
    int*   cursor = cnt;

    // fused preamble: xbf, tiled wsplits, zero sums, zero cnt, counts
    const int XB = (NN * 32 + 255) / 256;
    const int CB = (NN + 255) / 256;
    int pre_blocks = XB + 16 + 32 + 64 + CB + 1;
    k_preamble<<<pre_blocks, 256, 0, stream>>>(x, xbf, W1, w1hi, w1lo, W2, w2hi, w2lo,
                                               sums, cnt, batch, counts);

    // CSR build + dinv
    k_hist<<<(E + 255) / 256, 256, 0, stream>>>(dst, cnt, E);
    k_scan1<<<NB, 256, 0, stream>>>(cnt, bsum, N);
    k_scan2<<<1, 256, 0, stream>>>(bsum, NB);
    k_scan3<<<NB, 256, 0, stream>>>(cnt, bsum, rowptr, cursor, dinv, N);
    k_fill<<<(E + 255) / 256, 256, 0, stream>>>(src, dst, cursor, csr, E);

    // conv1: gather-aggregate xbf (128ch, 2 nodes/wave) -> bf16 A, reg-GEMM K=128 -> h1bf
    k_agg_gather<128><<<(N + 7) / 8, 256, 0, stream>>>(rowptr, csr, dinv, xbf, agg1, N);
    int gblocks = (N + 63) / 64;
    k_gemm_reg<false, 128><<<gblocks, 256, 0, stream>>>(agg1, w1hi, w1lo, b1, h1bf,
                                                        nullptr, nullptr, N);

    // conv2: gather-aggregate h1bf (256ch, 2 nodes/wave) -> bf16 A, reg-GEMM K=256 + pool
    k_agg_gather<256><<<(N + 7) / 8, 256, 0, stream>>>(rowptr, csr, dinv, h1bf, agg2, N);
    k_gemm_reg<true, 256><<<gblocks, 256, 0, stream>>>(agg2, w2hi, w2lo, b2, nullptr,
                                                       batch, sums, N);

    // dense head
    k_dense<<<G, 128, 0, stream>>>(sums, counts, W3, b3, W4, b4, out);
}

// Round 12
// 238.823 us; speedup vs baseline: 1.0174x; 1.0174x over previous
//
#include <hip/hip_runtime.h>

typedef unsigned short u16;
typedef unsigned int u32;
typedef __attribute__((ext_vector_type(8))) short s16x8;
typedef __attribute__((ext_vector_type(4))) float f32x4;

#define NN 50000
#define NE 600000
#define NG 64

__device__ __forceinline__ u16 f2bf(float f) {
    u32 u = __float_as_uint(f);
    u32 r = (u + 0x7fffu + ((u >> 16) & 1u)) >> 16;
    return (u16)r;
}
__device__ __forceinline__ float bf2f(u16 h) {
    return __uint_as_float(((u32)h) << 16);
}

// ---------------- CSR build ----------------
__global__ void k_hist(const int* __restrict__ dst, int* __restrict__ cnt, int ne) {
    int e = blockIdx.x * blockDim.x + threadIdx.x;
    if (e < ne) atomicAdd(&cnt[dst[e]], 1);
}

__global__ __launch_bounds__(256)
void k_scan1(const int* __restrict__ cnt, int* __restrict__ bsum, int n) {
    int i = blockIdx.x * 256 + threadIdx.x;
    int v = (i < n) ? cnt[i] : 0;
#pragma unroll
    for (int off = 32; off > 0; off >>= 1) v += __shfl_down(v, off, 64);
    __shared__ int ws[4];
    int lane = threadIdx.x & 63, w = threadIdx.x >> 6;
    if (lane == 0) ws[w] = v;
    __syncthreads();
    if (threadIdx.x == 0) bsum[blockIdx.x] = ws[0] + ws[1] + ws[2] + ws[3];
}

__global__ __launch_bounds__(256)
void k_scan2(int* __restrict__ bsum, int nb) {
    int t = threadIdx.x;
    int v = (t < nb) ? bsum[t] : 0;
    int lane = t & 63, w = t >> 6;
    int inc = v;
#pragma unroll
    for (int off = 1; off < 64; off <<= 1) {
        int x = __shfl_up(inc, off, 64);
        if (lane >= off) inc += x;
    }
    __shared__ int wtot[4];
    if (lane == 63) wtot[w] = inc;
    __syncthreads();
    int wo = 0;
    for (int j = 0; j < w; ++j) wo += wtot[j];
    if (t < nb) bsum[t] = wo + inc - v;   // exclusive
}

__global__ __launch_bounds__(256)
void k_scan3(const int* __restrict__ cnt, const int* __restrict__ boff,
             int* __restrict__ rowptr, int* __restrict__ cursor,
             float* __restrict__ dinv, int n) {
    int i = blockIdx.x * 256 + threadIdx.x;
    int v = (i < n) ? cnt[i] : 0;
    int lane = threadIdx.x & 63, w = threadIdx.x >> 6;
    int inc = v;
#pragma unroll
    for (int off = 1; off < 64; off <<= 1) {
        int x = __shfl_up(inc, off, 64);
        if (lane >= off) inc += x;
    }
    __shared__ int wtot[4];
    if (lane == 63) wtot[w] = inc;
    __syncthreads();
    int wo = boff[blockIdx.x];
    for (int j = 0; j < w; ++j) wo += wtot[j];
    if (i < n) {
        int excl = wo + inc - v;
        rowptr[i] = excl;
        cursor[i] = excl;
        dinv[i] = rsqrtf(1.0f + (float)v);
        if (i == n - 1) rowptr[n] = excl + v;
    }
}

__global__ void k_fill(const int* __restrict__ src, const int* __restrict__ dst,
                       int* __restrict__ cursor, int* __restrict__ csr_src, int ne) {
    int e = blockIdx.x * blockDim.x + threadIdx.x;
    if (e < ne) {
        int pos = atomicAdd(&cursor[dst[e]], 1);
        csr_src[pos] = src[e];
    }
}

// ---------------- fused preamble ----------------
// Weights stored PRE-TILED single-bf16: wt[kgrp][n][8] with k = kgrp*8 + j
__device__ __forceinline__ void wsplit_tiled(const float* __restrict__ W,
                                             u16* __restrict__ hi, int gid) {
    int n = gid & 255, kgrp = gid >> 8;
    int kbase = kgrp * 8;
#pragma unroll
    for (int j = 0; j < 8; ++j) {
        float w = W[(size_t)(kbase + j) * 256 + n];
        hi[(size_t)gid * 8 + j] = f2bf(w);
    }
}

// block ranges: [0,XB) xbf | [16) W1 | [32) W2 | [64) sums | [CB) cnt | [1] counts
__global__ __launch_bounds__(256)
void k_preamble(const float* __restrict__ x, u16* __restrict__ xbf,
                const float* __restrict__ W1, u16* __restrict__ w1hi,
                const float* __restrict__ W2, u16* __restrict__ w2hi,
                float* __restrict__ sums, int* __restrict__ cnt,
                const int* __restrict__ batch, float* __restrict__ counts) {
    const int XB = (NN * 32 + 255) / 256;        // x as float4: N*128/4 elems
    const int CB = (NN + 255) / 256;
    int b = blockIdx.x, t = threadIdx.x;
    if (b < XB) {
        int i = b * 256 + t;
        if (i < NN * 32) {
            float4 v = ((const float4*)x)[i];
            ushort4 o;
            o.x = f2bf(v.x); o.y = f2bf(v.y); o.z = f2bf(v.z); o.w = f2bf(v.w);
            ((ushort4*)xbf)[i] = o;
        }
        return;
    }
    b -= XB;
    if (b < 16) { wsplit_tiled(W1, w1hi, b * 256 + t); return; }   // 4096 groups
    b -= 16;
    if (b < 32) { wsplit_tiled(W2, w2hi, b * 256 + t); return; }   // 8192 groups
    b -= 32;
    if (b < 64) { sums[b * 256 + t] = 0.f; return; }
    b -= 64;
    if (b < CB) {
        int i = b * 256 + t;
        if (i < NN) cnt[i] = 0;
        return;
    }
    b -= CB;
    if (b == 0) {   // counts via binary search on sorted batch
        __shared__ int lb[65];
        if (t <= 64) {
            int lo = 0, hi = NN;
            while (lo < hi) {
                int mid = (lo + hi) >> 1;
                if (batch[mid] < t) lo = mid + 1; else hi = mid;
            }
            lb[t] = lo;
        }
        __syncthreads();
        if (t < 64) counts[t] = (float)(lb[t + 1] - lb[t]);
    }
}

// ---------------- gather aggregation: 2 nodes/wave, 32 lanes/node ----------------
__device__ __forceinline__ void fma8(float* a, const uint4& v, float w) {
    a[0] += bf2f((u16)v.x) * w; a[1] += bf2f((u16)(v.x >> 16)) * w;
    a[2] += bf2f((u16)v.y) * w; a[3] += bf2f((u16)(v.y >> 16)) * w;
    a[4] += bf2f((u16)v.z) * w; a[5] += bf2f((u16)(v.z >> 16)) * w;
    a[6] += bf2f((u16)v.w) * w; a[7] += bf2f((u16)(v.w >> 16)) * w;
}
__device__ __forceinline__ void fma4(float* a, const uint2& v, float w) {
    a[0] += bf2f((u16)v.x) * w; a[1] += bf2f((u16)(v.x >> 16)) * w;
    a[2] += bf2f((u16)v.y) * w; a[3] += bf2f((u16)(v.y >> 16)) * w;
}

template<int C>   // C=256: uint4/lane (8 bf16); C=128: uint2/lane (4 bf16)
__global__ __launch_bounds__(256)
void k_agg_gather(const int* __restrict__ rowptr, const int* __restrict__ csr_src,
                  const float* __restrict__ dinv, const u16* __restrict__ hb,
                  u16* __restrict__ out, int n) {
    constexpr int VL = C / 32;           // bf16 per lane (8 or 4)
    int tid = threadIdx.x;
    int node = (blockIdx.x * 256 + tid) >> 5;
    if (node >= n) return;
    int sl = tid & 31;                   // lane within node's 32-lane group
    int hbase = tid & 32;                // this half's lane base within the wave
    int beg = rowptr[node], end = rowptr[node + 1];
    int m = end - beg;
    float di = dinv[node];
    float a0[VL], a1[VL];
    if constexpr (VL == 8) {
        uint4 v = ((const uint4*)hb)[(size_t)node * 32 + sl];
#pragma unroll
        for (int i = 0; i < 8; ++i) a1[i] = 0.f;
        a0[0] = bf2f((u16)v.x) * di; a0[1] = bf2f((u16)(v.x >> 16)) * di;
        a0[2] = bf2f((u16)v.y) * di; a0[3] = bf2f((u16)(v.y >> 16)) * di;
        a0[4] = bf2f((u16)v.z) * di; a0[5] = bf2f((u16)(v.z >> 16)) * di;
        a0[6] = bf2f((u16)v.w) * di; a0[7] = bf2f((u16)(v.w >> 16)) * di;
    } else {
        uint2 v = ((const uint2*)hb)[(size_t)node * 32 + sl];
#pragma unroll
        for (int i = 0; i < 4; ++i) a1[i] = 0.f;
        a0[0] = bf2f((u16)v.x) * di; a0[1] = bf2f((u16)(v.x >> 16)) * di;
        a0[2] = bf2f((u16)v.y) * di; a0[3] = bf2f((u16)(v.y >> 16)) * di;
    }
    for (int base = 0; base < m; base += 32) {
        int c = m - base; if (c > 32) c = 32;
        int sid = 0; float w = 0.f;      // padding lanes: node 0 with weight 0 (harmless)
        if (sl < c) { sid = csr_src[beg + base + sl]; w = dinv[sid]; }
        int cr = (c + 3) & ~3;           // round up: no serial tail
        for (int e = 0; e < cr; e += 4) {
            int   s0 = __shfl(sid, hbase + e, 64),     s1 = __shfl(sid, hbase + e + 1, 64);
            int   s2 = __shfl(sid, hbase + e + 2, 64), s3 = __shfl(sid, hbase + e + 3, 64);
            float w0 = __shfl(w, hbase + e, 64),       w1 = __shfl(w, hbase + e + 1, 64);
            float w2 = __shfl(w, hbase + e + 2, 64),   w3 = __shfl(w, hbase + e + 3, 64);
            if constexpr (VL == 8) {
                uint4 r0 = ((const uint4*)hb)[(size_t)s0 * 32 + sl];
                uint4 r1 = ((const uint4*)hb)[(size_t)s1 * 32 + sl];
                uint4 r2 = ((const uint4*)hb)[(size_t)s2 * 32 + sl];
                uint4 r3 = ((const uint4*)hb)[(size_t)s3 * 32 + sl];
                fma8(a0, r0, w0); fma8(a1, r1, w1); fma8(a0, r2, w2); fma8(a1, r3, w3);
            } else {
                uint2 r0 = ((const uint2*)hb)[(size_t)s0 * 32 + sl];
                uint2 r1 = ((const uint2*)hb)[(size_t)s1 * 32 + sl];
                uint2 r2 = ((const uint2*)hb)[(size_t)s2 * 32 + sl];
                uint2 r3 = ((const uint2*)hb)[(size_t)s3 * 32 + sl];
                fma4(a0, r0, w0); fma4(a1, r1, w1); fma4(a0, r2, w2); fma4(a1, r3, w3);
            }
        }
    }
    if constexpr (VL == 8) {
        uint4 o;
        o.x = (u32)f2bf((a0[0] + a1[0]) * di) | ((u32)f2bf((a0[1] + a1[1]) * di) << 16);
        o.y = (u32)f2bf((a0[2] + a1[2]) * di) | ((u32)f2bf((a0[3] + a1[3]) * di) << 16);
        o.z = (u32)f2bf((a0[4] + a1[4]) * di) | ((u32)f2bf((a0[5] + a1[5]) * di) << 16);
        o.w = (u32)f2bf((a0[6] + a1[6]) * di) | ((u32)f2bf((a0[7] + a1[7]) * di) << 16);
        ((uint4*)out)[(size_t)node * 32 + sl] = o;
    } else {
        uint2 o;
        o.x = (u32)f2bf((a0[0] + a1[0]) * di) | ((u32)f2bf((a0[1] + a1[1]) * di) << 16);
        o.y = (u32)f2bf((a0[2] + a1[2]) * di) | ((u32)f2bf((a0[3] + a1[3]) * di) << 16);
        ((uint2*)out)[(size_t)node * 32 + sl] = o;
    }
}

// ---------------- register MFMA GEMM: BM=64, BN=256, 256 thr / 4 waves ----------------
// NO LDS, NO barriers. Single-bf16 B (half the operand traffic and MFMA count of the
// split version); fp32 MFMA accumulate. Full K unroll; latency hidden by TLP.
template<bool POOL, int KK>
__global__ __launch_bounds__(256)
void k_gemm_reg(const u16* __restrict__ A, const u16* __restrict__ Bhi,
                const float* __restrict__ bias, u16* __restrict__ out_bf,
                const int* __restrict__ batch, float* __restrict__ pool,
                int M) {
    const int lane = threadIdx.x & 63, wid = threadIdx.x >> 6;
    const int bm = blockIdx.x * 64;
    const int wc = wid * 64;
    const int lr = lane & 15, kg = lane >> 4;

    // per-fm A row addresses (clamped)
    const u16* arow[4];
#pragma unroll
    for (int fm = 0; fm < 4; ++fm) {
        int row = bm + fm * 16 + lr;
        if (row >= M) row = M - 1;
        arow[fm] = A + (size_t)row * KK + kg * 8;
    }
    // B fragment base: pre-tiled idx = ((t*4+kg)*256 + wc+fn*16+lr)*8
    const u16* bh_p = Bhi + ((u32)kg * 256 + wc + lr) * 8;

    f32x4 acc[4][4];
#pragma unroll
    for (int i = 0; i < 4; ++i)
#pragma unroll
        for (int j = 0; j < 4; ++j) acc[i][j] = (f32x4){0.f, 0.f, 0.f, 0.f};

#pragma unroll
    for (int t = 0; t < KK / 32; ++t) {
        s16x8 a[4], bh[4];
#pragma unroll
        for (int fm = 0; fm < 4; ++fm)
            a[fm] = *(const s16x8*)(arow[fm] + t * 32);
#pragma unroll
        for (int fn = 0; fn < 4; ++fn)
            bh[fn] = *(const s16x8*)&bh_p[(u32)t * 8192 + (u32)fn * 128];
#pragma unroll
        for (int fn = 0; fn < 4; ++fn)
#pragma unroll
            for (int fm = 0; fm < 4; ++fm)
                acc[fm][fn] = __builtin_amdgcn_mfma_f32_16x16x32_bf16(a[fm], bh[fn], acc[fm][fn], 0, 0, 0);
    }

    // epilogue: row = bm + fm*16 + kg*4 + r ; col = wc + fn*16 + lr
#pragma unroll
    for (int fn = 0; fn < 4; ++fn) {
        int col = wc + fn * 16 + lr;
        float bv = bias[col];
        if (!POOL) {
#pragma unroll
            for (int fm = 0; fm < 4; ++fm) {
                int rbase = bm + fm * 16 + kg * 4;
#pragma unroll
                for (int r = 0; r < 4; ++r) {
                    int row = rbase + r;
                    if (row < M)
                        out_bf[(size_t)row * 256 + col] = f2bf(fmaxf(acc[fm][fn][r] + bv, 0.f));
                }
            }
        } else {
            int gcur = -1;
            float run = 0.f;
#pragma unroll
            for (int fm = 0; fm < 4; ++fm) {
                int rbase = bm + fm * 16 + kg * 4;
#pragma unroll
                for (int r = 0; r < 4; ++r) {
                    int row = rbase + r;
                    if (row < M) {
                        int g = batch[row];
                        float v = fmaxf(acc[fm][fn][r] + bv, 0.f);
                        if (g != gcur) {
                            if (gcur >= 0) atomicAdd(&pool[gcur * 256 + col], run);
                            gcur = g;
                            run = 0.f;
                        }
                        run += v;
                    }
                }
            }
            if (gcur >= 0) atomicAdd(&pool[gcur * 256 + col], run);
        }
    }
}

// ---------------- dense head ----------------
__global__ __launch_bounds__(128)
void k_dense(const float* __restrict__ sums, const float* __restrict__ counts,
             const float* __restrict__ W3, const float* __restrict__ b3,
             const float* __restrict__ W4, const float* __restrict__ b4,
             float* __restrict__ out) {
    __shared__ float g[256];
    __shared__ float hid[128];
    int gi = blockIdx.x;
    int t = threadIdx.x;
    float inv = 1.0f / fmaxf(counts[gi], 1.0f);
    for (int c = t; c < 256; c += 128) g[c] = sums[gi * 256 + c] * inv;
    __syncthreads();
    float acc = b3[t];
    for (int k = 0; k < 256; ++k) acc += g[k] * W3[k * 128 + t];
    hid[t] = fmaxf(acc, 0.0f);
    __syncthreads();
    if (t < 10) {
        float o = b4[t];
        for (int k = 0; k < 128; ++k) o += hid[k] * W4[k * 10 + t];
        out[gi * 10 + t] = o;
    }
}

extern "C" void kernel_launch(void* const* d_in, const int* in_sizes, int n_in,
                              void* d_out, int out_size, void* d_ws, size_t ws_size,
                              hipStream_t stream) {
    const float* x   = (const float*)d_in[0];
    const int*  eidx = (const int*)d_in[1];    // [2, NE]
    const int*  batch= (const int*)d_in[2];
    const float* W1 = (const float*)d_in[3];
    const float* b1 = (const float*)d_in[4];
    const float* W2 = (const float*)d_in[5];
    const float* b2 = (const float*)d_in[6];
    const float* W3 = (const float*)d_in[7];
    const float* b3 = (const float*)d_in[8];
    const float* W4 = (const float*)d_in[9];
    const float* b4 = (const float*)d_in[10];
    float* out = (float*)d_out;

    const int N = NN, E = NE, G = NG;
    const int* src = eidx;
    const int* dst = eidx + E;
    const int NB = (N + 255) / 256;

    // workspace layout (256B-aligned slices)
    char* p = (char*)d_ws;
    auto alloc = [&](size_t bytes) { char* r = p; p += (bytes + 255) & ~(size_t)255; return r; };
    u16*   h1bf   = (u16*)alloc((size_t)N * 256 * 2);   // bf16 h1 (gather source for conv2)
    u16*   xbf    = (u16*)alloc((size_t)N * 128 * 2);   // bf16 x  (gather source for conv1)
    float* dinv   = (float*)alloc((size_t)N * 4);
    float* sums   = (float*)alloc((size_t)G * 256 * 4);
    float* counts = (float*)alloc((size_t)G * 4);
    int*   cnt    = (int*)alloc((size_t)N * 4);         // reused as cursor after scan
    int*   rowptr = (int*)alloc((size_t)(N + 1) * 4);
    int*   bsum   = (int*)alloc((size_t)NB * 4);
    int*   csr    = (int*)alloc((size_t)E * 4);
    u16*   agg1   = (u16*)alloc((size_t)N * 128 * 2);   // bf16 aggregated x (GEMM1 A)
    u16*   agg2   = (u16*)alloc((size_t)N * 256 * 2);   // bf16 aggregated h1 (GEMM2 A)
    u16*   w1hi   = (u16*)alloc((size_t)256 * 128 * 2); // pre-tiled [kgrp][n][8]
    u16*   w2hi   = (u16*)alloc((size_t)256 * 256 * 2);
    int*   cursor = cnt;

    // fused preamble: xbf, tiled wsplits (single bf16), zero sums, zero cnt, counts
    const int XB = (NN * 32 + 255) / 256;
    const int CB = (NN + 255) / 256;
    int pre_blocks = XB + 16 + 32 + 64 + CB + 1;
    k_preamble<<<pre_blocks, 256, 0, stream>>>(x, xbf, W1, w1hi, W2, w2hi,
                                               sums, cnt, batch, counts);

    // CSR build + dinv
    k_hist<<<(E + 255) / 256, 256, 0, stream>>>(dst, cnt, E);
    k_scan1<<<NB, 256, 0, stream>>>(cnt, bsum, N);
    k_scan2<<<1, 256, 0, stream>>>(bsum, NB);
    k_scan3<<<NB, 256, 0, stream>>>(cnt, bsum, rowptr, cursor, dinv, N);
    k_fill<<<(E + 255) / 256, 256, 0, stream>>>(src, dst, cursor, csr, E);

    // conv1: gather-aggregate xbf (128ch, 2 nodes/wave) -> bf16 A, reg-GEMM K=128 -> h1bf
    k_agg_gather<128><<<(N + 7) / 8, 256, 0, stream>>>(rowptr, csr, dinv, xbf, agg1, N);
    int gblocks = (N + 63) / 64;
    k_gemm_reg<false, 128><<<gblocks, 256, 0, stream>>>(agg1, w1hi, b1, h1bf,
                                                        nullptr, nullptr, N);

    // conv2: gather-aggregate h1bf (256ch, 2 nodes/wave) -> bf16 A, reg-GEMM K=256 + pool
    k_agg_gather<256><<<(N + 7) / 8, 256, 0, stream>>>(rowptr, csr, dinv, h1bf, agg2, N);
    k_gemm_reg<true, 256><<<gblocks, 256, 0, stream>>>(agg2, w2hi, b2, nullptr,
                                                       batch, sums, N);

    // dense head
    k_dense<<<G, 128, 0, stream>>>(sums, counts, W3, b3, W4, b4, out);
}

// Round 13
// 213.640 us; speedup vs baseline: 1.1373x; 1.1179x over previous
//
#include <hip/hip_runtime.h>

typedef unsigned short u16;
typedef unsigned int u32;
typedef __attribute__((ext_vector_type(8))) short s16x8;
typedef __attribute__((ext_vector_type(4))) float f32x4;

#define NN 50000
#define NE 600000
#define NG 64

__device__ __forceinline__ u16 f2bf(float f) {
    u32 u = __float_as_uint(f);
    u32 r = (u + 0x7fffu + ((u >> 16) & 1u)) >> 16;
    return (u16)r;
}
__device__ __forceinline__ float bf2f(u16 h) {
    return __uint_as_float(((u32)h) << 16);
}
__device__ __forceinline__ void gll16(const void* g, void* l) {
    __builtin_amdgcn_global_load_lds((const __attribute__((address_space(1))) u32*)g,
                                     (__attribute__((address_space(3))) u32*)l, 16, 0, 0);
}

// ---------------- CSR build ----------------
__global__ void k_hist(const int* __restrict__ dst, int* __restrict__ cnt, int ne) {
    int e = blockIdx.x * blockDim.x + threadIdx.x;
    if (e < ne) atomicAdd(&cnt[dst[e]], 1);
}

__global__ __launch_bounds__(256)
void k_scan1(const int* __restrict__ cnt, int* __restrict__ bsum, int n) {
    int i = blockIdx.x * 256 + threadIdx.x;
    int v = (i < n) ? cnt[i] : 0;
#pragma unroll
    for (int off = 32; off > 0; off >>= 1) v += __shfl_down(v, off, 64);
    __shared__ int ws[4];
    int lane = threadIdx.x & 63, w = threadIdx.x >> 6;
    if (lane == 0) ws[w] = v;
    __syncthreads();
    if (threadIdx.x == 0) bsum[blockIdx.x] = ws[0] + ws[1] + ws[2] + ws[3];
}

__global__ __launch_bounds__(256)
void k_scan2(int* __restrict__ bsum, int nb) {
    int t = threadIdx.x;
    int v = (t < nb) ? bsum[t] : 0;
    int lane = t & 63, w = t >> 6;
    int inc = v;
#pragma unroll
    for (int off = 1; off < 64; off <<= 1) {
        int x = __shfl_up(inc, off, 64);
        if (lane >= off) inc += x;
    }
    __shared__ int wtot[4];
    if (lane == 63) wtot[w] = inc;
    __syncthreads();
    int wo = 0;
    for (int j = 0; j < w; ++j) wo += wtot[j];
    if (t < nb) bsum[t] = wo + inc - v;   // exclusive
}

__global__ __launch_bounds__(256)
void k_scan3(const int* __restrict__ cnt, const int* __restrict__ boff,
             int* __restrict__ rowptr, int* __restrict__ cursor,
             float* __restrict__ dinv, int n) {
    int i = blockIdx.x * 256 + threadIdx.x;
    int v = (i < n) ? cnt[i] : 0;
    int lane = threadIdx.x & 63, w = threadIdx.x >> 6;
    int inc = v;
#pragma unroll
    for (int off = 1; off < 64; off <<= 1) {
        int x = __shfl_up(inc, off, 64);
        if (lane >= off) inc += x;
    }
    __shared__ int wtot[4];
    if (lane == 63) wtot[w] = inc;
    __syncthreads();
    int wo = boff[blockIdx.x];
    for (int j = 0; j < w; ++j) wo += wtot[j];
    if (i < n) {
        int excl = wo + inc - v;
        rowptr[i] = excl;
        cursor[i] = excl;
        dinv[i] = rsqrtf(1.0f + (float)v);
        if (i == n - 1) rowptr[n] = excl + v;
    }
}

__global__ void k_fill(const int* __restrict__ src, const int* __restrict__ dst,
                       int* __restrict__ cursor, int* __restrict__ csr_src, int ne) {
    int e = blockIdx.x * blockDim.x + threadIdx.x;
    if (e < ne) {
        int pos = atomicAdd(&cursor[dst[e]], 1);
        csr_src[pos] = src[e];
    }
}

// ---------------- fused preamble ----------------
// Weights stored PRE-TILED single-bf16: wt[kgrp][n][8] with k = kgrp*8 + j
__device__ __forceinline__ void wsplit_tiled(const float* __restrict__ W,
                                             u16* __restrict__ hi, int gid) {
    int n = gid & 255, kgrp = gid >> 8;
    int kbase = kgrp * 8;
#pragma unroll
    for (int j = 0; j < 8; ++j) {
        float w = W[(size_t)(kbase + j) * 256 + n];
        hi[(size_t)gid * 8 + j] = f2bf(w);
    }
}

// block ranges: [0,XB) xbf | [16) W1 | [32) W2 | [64) sums | [CB) cnt | [1] counts
__global__ __launch_bounds__(256)
void k_preamble(const float* __restrict__ x, u16* __restrict__ xbf,
                const float* __restrict__ W1, u16* __restrict__ w1hi,
                const float* __restrict__ W2, u16* __restrict__ w2hi,
                float* __restrict__ sums, int* __restrict__ cnt,
                const int* __restrict__ batch, float* __restrict__ counts) {
    const int XB = (NN * 32 + 255) / 256;        // x as float4: N*128/4 elems
    const int CB = (NN + 255) / 256;
    int b = blockIdx.x, t = threadIdx.x;
    if (b < XB) {
        int i = b * 256 + t;
        if (i < NN * 32) {
            float4 v = ((const float4*)x)[i];
            ushort4 o;
            o.x = f2bf(v.x); o.y = f2bf(v.y); o.z = f2bf(v.z); o.w = f2bf(v.w);
            ((ushort4*)xbf)[i] = o;
        }
        return;
    }
    b -= XB;
    if (b < 16) { wsplit_tiled(W1, w1hi, b * 256 + t); return; }   // 4096 groups
    b -= 16;
    if (b < 32) { wsplit_tiled(W2, w2hi, b * 256 + t); return; }   // 8192 groups
    b -= 32;
    if (b < 64) { sums[b * 256 + t] = 0.f; return; }
    b -= 64;
    if (b < CB) {
        int i = b * 256 + t;
        if (i < NN) cnt[i] = 0;
        return;
    }
    b -= CB;
    if (b == 0) {   // counts via binary search on sorted batch
        __shared__ int lb[65];
        if (t <= 64) {
            int lo = 0, hi = NN;
            while (lo < hi) {
                int mid = (lo + hi) >> 1;
                if (batch[mid] < t) lo = mid + 1; else hi = mid;
            }
            lb[t] = lo;
        }
        __syncthreads();
        if (t < 64) counts[t] = (float)(lb[t + 1] - lb[t]);
    }
}

// ---------------- gather aggregation: 2 nodes/wave, 32 lanes/node ----------------
__device__ __forceinline__ void fma8(float* a, const uint4& v, float w) {
    a[0] += bf2f((u16)v.x) * w; a[1] += bf2f((u16)(v.x >> 16)) * w;
    a[2] += bf2f((u16)v.y) * w; a[3] += bf2f((u16)(v.y >> 16)) * w;
    a[4] += bf2f((u16)v.z) * w; a[5] += bf2f((u16)(v.z >> 16)) * w;
    a[6] += bf2f((u16)v.w) * w; a[7] += bf2f((u16)(v.w >> 16)) * w;
}
__device__ __forceinline__ void fma4(float* a, const uint2& v, float w) {
    a[0] += bf2f((u16)v.x) * w; a[1] += bf2f((u16)(v.x >> 16)) * w;
    a[2] += bf2f((u16)v.y) * w; a[3] += bf2f((u16)(v.y >> 16)) * w;
}

template<int C>   // C=256: uint4/lane (8 bf16); C=128: uint2/lane (4 bf16)
__global__ __launch_bounds__(256)
void k_agg_gather(const int* __restrict__ rowptr, const int* __restrict__ csr_src,
                  const float* __restrict__ dinv, const u16* __restrict__ hb,
                  u16* __restrict__ out, int n) {
    constexpr int VL = C / 32;           // bf16 per lane (8 or 4)
    int tid = threadIdx.x;
    int node = (blockIdx.x * 256 + tid) >> 5;
    if (node >= n) return;
    int sl = tid & 31;                   // lane within node's 32-lane group
    int hbase = tid & 32;                // this half's lane base within the wave
    int beg = rowptr[node], end = rowptr[node + 1];
    int m = end - beg;
    float di = dinv[node];
    float a0[VL], a1[VL];
    if constexpr (VL == 8) {
        uint4 v = ((const uint4*)hb)[(size_t)node * 32 + sl];
#pragma unroll
        for (int i = 0; i < 8; ++i) a1[i] = 0.f;
        a0[0] = bf2f((u16)v.x) * di; a0[1] = bf2f((u16)(v.x >> 16)) * di;
        a0[2] = bf2f((u16)v.y) * di; a0[3] = bf2f((u16)(v.y >> 16)) * di;
        a0[4] = bf2f((u16)v.z) * di; a0[5] = bf2f((u16)(v.z >> 16)) * di;
        a0[6] = bf2f((u16)v.w) * di; a0[7] = bf2f((u16)(v.w >> 16)) * di;
    } else {
        uint2 v = ((const uint2*)hb)[(size_t)node * 32 + sl];
#pragma unroll
        for (int i = 0; i < 4; ++i) a1[i] = 0.f;
        a0[0] = bf2f((u16)v.x) * di; a0[1] = bf2f((u16)(v.x >> 16)) * di;
        a0[2] = bf2f((u16)v.y) * di; a0[3] = bf2f((u16)(v.y >> 16)) * di;
    }
    for (int base = 0; base < m; base += 32) {
        int c = m - base; if (c > 32) c = 32;
        int sid = 0; float w = 0.f;      // padding lanes: node 0 with weight 0 (harmless)
        if (sl < c) { sid = csr_src[beg + base + sl]; w = dinv[sid]; }
        int cr = (c + 3) & ~3;           // round up: no serial tail
        for (int e = 0; e < cr; e += 4) {
            int   s0 = __shfl(sid, hbase + e, 64),     s1 = __shfl(sid, hbase + e + 1, 64);
            int   s2 = __shfl(sid, hbase + e + 2, 64), s3 = __shfl(sid, hbase + e + 3, 64);
            float w0 = __shfl(w, hbase + e, 64),       w1 = __shfl(w, hbase + e + 1, 64);
            float w2 = __shfl(w, hbase + e + 2, 64),   w3 = __shfl(w, hbase + e + 3, 64);
            if constexpr (VL == 8) {
                uint4 r0 = ((const uint4*)hb)[(size_t)s0 * 32 + sl];
                uint4 r1 = ((const uint4*)hb)[(size_t)s1 * 32 + sl];
                uint4 r2 = ((const uint4*)hb)[(size_t)s2 * 32 + sl];
                uint4 r3 = ((const uint4*)hb)[(size_t)s3 * 32 + sl];
                fma8(a0, r0, w0); fma8(a1, r1, w1); fma8(a0, r2, w2); fma8(a1, r3, w3);
            } else {
                uint2 r0 = ((const uint2*)hb)[(size_t)s0 * 32 + sl];
                uint2 r1 = ((const uint2*)hb)[(size_t)s1 * 32 + sl];
                uint2 r2 = ((const uint2*)hb)[(size_t)s2 * 32 + sl];
                uint2 r3 = ((const uint2*)hb)[(size_t)s3 * 32 + sl];
                fma4(a0, r0, w0); fma4(a1, r1, w1); fma4(a0, r2, w2); fma4(a1, r3, w3);
            }
        }
    }
    if constexpr (VL == 8) {
        uint4 o;
        o.x = (u32)f2bf((a0[0] + a1[0]) * di) | ((u32)f2bf((a0[1] + a1[1]) * di) << 16);
        o.y = (u32)f2bf((a0[2] + a1[2]) * di) | ((u32)f2bf((a0[3] + a1[3]) * di) << 16);
        o.z = (u32)f2bf((a0[4] + a1[4]) * di) | ((u32)f2bf((a0[5] + a1[5]) * di) << 16);
        o.w = (u32)f2bf((a0[6] + a1[6]) * di) | ((u32)f2bf((a0[7] + a1[7]) * di) << 16);
        ((uint4*)out)[(size_t)node * 32 + sl] = o;
    } else {
        uint2 o;
        o.x = (u32)f2bf((a0[0] + a1[0]) * di) | ((u32)f2bf((a0[1] + a1[1]) * di) << 16);
        o.y = (u32)f2bf((a0[2] + a1[2]) * di) | ((u32)f2bf((a0[3] + a1[3]) * di) << 16);
        ((uint2*)out)[(size_t)node * 32 + sl] = o;
    }
}

// ---------------- MFMA GEMM (R9 structure, single-bf16 B) ----------------
// BM=128, BN=256, BK=32, 512 thr / 8 waves. A staged in 16KB dbuf LDS via
// global_load_lds (64B-granular chunks, XOR source-slot swizzle -> <=2-way ds_read
// conflicts). B = pre-tiled [kgrp][n][8] bf16, read straight to VGPRs from L2.
// One MFMA per fragment pair (single-bf16 weights), fp32 accumulate.
template<bool POOL>
__global__ __launch_bounds__(512, 4)
void k_gemm_mfma(const u16* __restrict__ A, const u16* __restrict__ Bh,
                 const float* __restrict__ bias, u16* __restrict__ out_bf,
                 const int* __restrict__ batch, float* __restrict__ pool,
                 int M, int K) {
    __shared__ u16 ldsA[2][4096];   // 2 x 8KB: [128 rows][4 slots of 8 bf16]
    const int tid = threadIdx.x, lane = tid & 63, wid = tid >> 6;
    const int bm = blockIdx.x * 128;
    const int wr = (wid >> 2) * 64, wc = (wid & 3) * 64;
    const int lr = lane & 15, kg = lane >> 4;

    // per-wave A-stage addressing: wave wid stages rows wid*16..+15 (1KB chunk)
    const int srow = wid * 16 + (lane >> 2);            // local row 0..127
    const int sslot = lane & 3;
    const int ssw = (srow ^ (srow >> 2)) & 3;
    int srg = bm + srow; if (srg >= M) srg = M - 1;
    const u16* sbase = A + (size_t)srg * K + ((sslot ^ ssw) << 3);

    // B fragment base (pre-tiled [kgrp][n][8]): idx = (t*4+kg)*2048 + (wc+fn*16+lr)*8
    const u16* bh_p = Bh + (u32)kg * 2048 + (u32)(wc + lr) * 8;

    f32x4 acc[4][4];
#pragma unroll
    for (int i = 0; i < 4; ++i)
#pragma unroll
        for (int j = 0; j < 4; ++j) acc[i][j] = (f32x4){0.f, 0.f, 0.f, 0.f};

    const int nt = K >> 5;
    gll16(sbase, &ldsA[0][wid * 512]);     // prologue: stage tile 0
    __syncthreads();

    for (int t = 0; t < nt; ++t) {
        int cur = t & 1;
        if (t + 1 < nt)
            gll16(sbase + ((t + 1) << 5), &ldsA[cur ^ 1][wid * 512]);

        // B fragments straight from L2 (contiguous 256B per 16-lane group)
        s16x8 bh[4];
#pragma unroll
        for (int fn = 0; fn < 4; ++fn)
            bh[fn] = *(const s16x8*)&bh_p[(u32)t * 8192 + (u32)fn * 128];
        // A fragments from LDS (swizzled slots)
        const u16* lb = ldsA[cur];
        s16x8 a[4];
#pragma unroll
        for (int fm = 0; fm < 4; ++fm) {
            int r = wr + fm * 16 + lr;
            a[fm] = *(const s16x8*)&lb[r * 32 + ((kg ^ ((r ^ (r >> 2)) & 3)) << 3)];
        }
#pragma unroll
        for (int fn = 0; fn < 4; ++fn)
#pragma unroll
            for (int fm = 0; fm < 4; ++fm)
                acc[fm][fn] = __builtin_amdgcn_mfma_f32_16x16x32_bf16(a[fm], bh[fn], acc[fm][fn], 0, 0, 0);
        __syncthreads();
    }

    // epilogue: row = bm + wr + fm*16 + kg*4 + r ; col = wc + fn*16 + lr
#pragma unroll
    for (int fn = 0; fn < 4; ++fn) {
        int col = wc + fn * 16 + lr;
        float bv = bias[col];
        if (!POOL) {
#pragma unroll
            for (int fm = 0; fm < 4; ++fm) {
                int rbase = bm + wr + fm * 16 + kg * 4;
#pragma unroll
                for (int r = 0; r < 4; ++r) {
                    int row = rbase + r;
                    if (row < M)
                        out_bf[(size_t)row * 256 + col] = f2bf(fmaxf(acc[fm][fn][r] + bv, 0.f));
                }
            }
        } else {
            int gcur = -1;
            float run = 0.f;
#pragma unroll
            for (int fm = 0; fm < 4; ++fm) {
                int rbase = bm + wr + fm * 16 + kg * 4;
#pragma unroll
                for (int r = 0; r < 4; ++r) {
                    int row = rbase + r;
                    if (row < M) {
                        int g = batch[row];
                        float v = fmaxf(acc[fm][fn][r] + bv, 0.f);
                        if (g != gcur) {
                            if (gcur >= 0) atomicAdd(&pool[gcur * 256 + col], run);
                            gcur = g;
                            run = 0.f;
                        }
                        run += v;
                    }
                }
            }
            if (gcur >= 0) atomicAdd(&pool[gcur * 256 + col], run);
        }
    }
}

// ---------------- dense head ----------------
__global__ __launch_bounds__(128)
void k_dense(const float* __restrict__ sums, const float* __restrict__ counts,
             const float* __restrict__ W3, const float* __restrict__ b3,
             const float* __restrict__ W4, const float* __restrict__ b4,
             float* __restrict__ out) {
    __shared__ float g[256];
    __shared__ float hid[128];
    int gi = blockIdx.x;
    int t = threadIdx.x;
    float inv = 1.0f / fmaxf(counts[gi], 1.0f);
    for (int c = t; c < 256; c += 128) g[c] = sums[gi * 256 + c] * inv;
    __syncthreads();
    float acc = b3[t];
    for (int k = 0; k < 256; ++k) acc += g[k] * W3[k * 128 + t];
    hid[t] = fmaxf(acc, 0.0f);
    __syncthreads();
    if (t < 10) {
        float o = b4[t];
        for (int k = 0; k < 128; ++k) o += hid[k] * W4[k * 10 + t];
        out[gi * 10 + t] = o;
    }
}

extern "C" void kernel_launch(void* const* d_in, const int* in_sizes, int n_in,
                              void* d_out, int out_size, void* d_ws, size_t ws_size,
                              hipStream_t stream) {
    const float* x   = (const float*)d_in[0];
    const int*  eidx = (const int*)d_in[1];    // [2, NE]
    const int*  batch= (const int*)d_in[2];
    const float* W1 = (const float*)d_in[3];
    const float* b1 = (const float*)d_in[4];
    const float* W2 = (const float*)d_in[5];
    const float* b2 = (const float*)d_in[6];
    const float* W3 = (const float*)d_in[7];
    const float* b3 = (const float*)d_in[8];
    const float* W4 = (const float*)d_in[9];
    const float* b4 = (const float*)d_in[10];
    float* out = (float*)d_out;

    const int N = NN, E = NE, G = NG;
    const int* src = eidx;
    const int* dst = eidx + E;
    const int NB = (N + 255) / 256;

    // workspace layout (256B-aligned slices)
    char* p = (char*)d_ws;
    auto alloc = [&](size_t bytes) { char* r = p; p += (bytes + 255) & ~(size_t)255; return r; };
    u16*   h1bf   = (u16*)alloc((size_t)N * 256 * 2);   // bf16 h1 (gather source for conv2)
    u16*   xbf    = (u16*)alloc((size_t)N * 128 * 2);   // bf16 x  (gather source for conv1)
    float* dinv   = (float*)alloc((size_t)N * 4);
    float* sums   = (float*)alloc((size_t)G * 256 * 4);
    float* counts = (float*)alloc((size_t)G * 4);
    int*   cnt    = (int*)alloc((size_t)N * 4);         // reused as cursor after scan
    int*   rowptr = (int*)alloc((size_t)(N + 1) * 4);
    int*   bsum   = (int*)alloc((size_t)NB * 4);
    int*   csr    = (int*)alloc((size_t)E * 4);
    u16*   agg1   = (u16*)alloc((size_t)N * 128 * 2);   // bf16 aggregated x (GEMM1 A)
    u16*   agg2   = (u16*)alloc((size_t)N * 256 * 2);   // bf16 aggregated h1 (GEMM2 A)
    u16*   w1hi   = (u16*)alloc((size_t)256 * 128 * 2); // pre-tiled [kgrp][n][8]
    u16*   w2hi   = (u16*)alloc((size_t)256 * 256 * 2);
    int*   cursor = cnt;

    // fused preamble: xbf, tiled wsplits (single bf16), zero sums, zero cnt, counts
    const int XB = (NN * 32 + 255) / 256;
    const int CB = (NN + 255) / 256;
    int pre_blocks = XB + 16 + 32 + 64 + CB + 1;
    k_preamble<<<pre_blocks, 256, 0, stream>>>(x, xbf, W1, w1hi, W2, w2hi,
                                               sums, cnt, batch, counts);

    // CSR build + dinv
    k_hist<<<(E + 255) / 256, 256, 0, stream>>>(dst, cnt, E);
    k_scan1<<<NB, 256, 0, stream>>>(cnt, bsum, N);
    k_scan2<<<1, 256, 0, stream>>>(bsum, NB);
    k_scan3<<<NB, 256, 0, stream>>>(cnt, bsum, rowptr, cursor, dinv, N);
    k_fill<<<(E + 255) / 256, 256, 0, stream>>>(src, dst, cursor, csr, E);

    // conv1: gather-aggregate xbf (128ch, 2 nodes/wave) -> bf16 A, GEMM K=128 -> h1bf
    k_agg_gather<128><<<(N + 7) / 8, 256, 0, stream>>>(rowptr, csr, dinv, xbf, agg1, N);
    int gblocks = (N + 127) / 128;
    k_gemm_mfma<false><<<gblocks, 512, 0, stream>>>(agg1, w1hi, b1, h1bf,
                                                    nullptr, nullptr, N, 128);

    // conv2: gather-aggregate h1bf (256ch, 2 nodes/wave) -> bf16 A, GEMM K=256 + pool
    k_agg_gather<256><<<(N + 7) / 8, 256, 0, stream>>>(rowptr, csr, dinv, h1bf, agg2, N);
    k_gemm_mfma<true><<<gblocks, 512, 0, stream>>>(agg2, w2hi, b2, nullptr,
                                                   batch, sums, N, 256);

    // dense head
    k_dense<<<G, 128, 0, stream>>>(sums, counts, W3, b3, W4, b4, out);
}